// Round 3
// baseline (790.037 us; speedup 1.0000x reference)
//
#include <hip/hip_runtime.h>

#define NN 10000
#define NE 160000

#define INV8   0.35355339059327373f   // 1/sqrt(8)
#define QINV   0.125f                 // 1/sqrt(64)
#define GAIN   1.679177f
#define ISQ3   0.57735026918962576f   // 1/sqrt(3)
#define FINALS 4.8828125e-5f          // 0.1 * (1/sqrt(512)) * (1/sqrt(128)) * 0.125
#define MPSC   2.2097086912079612e-4f // 0.01 / sqrt(2048)

__device__ __forceinline__ float4 ld4(const float* p){ return *(const float4*)p; }
__device__ __forceinline__ float sil(float x){ return x*GAIN/(1.f+__expf(-x)); }
__device__ __forceinline__ float rfl(float x){
  return __uint_as_float(__builtin_amdgcn_readfirstlane(__float_as_uint(x)));
}
#define C4(v,i) (((const float*)&(v))[i])

// Record layout per node (quad-major, 48 floats per u-quad, 16 quads = 768 floats):
//   S[n][uq]: [0:4]=l1s [4:16]=l1v(3 planes) [16:20]=qA_lo [20:24]=qA_hi*ISQ3
//             [24:36]=rA_lo*ISQ3 (3 planes)  [36:48]=rA_hi*ISQ3 (3 planes)
//   R[n][uq]: same with l2s/l2v/qB/rB.   (identical to the verified round-2 layout)

// ---------------- node kernel: lane = v/U, LDS-staged weights ----------------
__global__ __launch_bounds__(256, 2) void node_kernel(
    const float* __restrict__ nf, const float* __restrict__ ff,
    const float* __restrict__ W1s, const float* __restrict__ W1v,
    const float* __restrict__ W2s, const float* __restrict__ W2v,
    const float* __restrict__ Wvss, const float* __restrict__ Wvsv,
    const float* __restrict__ Wvrs, const float* __restrict__ Wvrv,
    const float* __restrict__ Wfs0, const float* __restrict__ Wfs1,
    const float* __restrict__ Wfr0, const float* __restrict__ Wfr1,
    const float* __restrict__ Wmsv, const float* __restrict__ Wmvs,
    float* __restrict__ wsS, float* __restrict__ wsR,
    float* __restrict__ out)
{
  __shared__ float lds[16384];          // 64 KB, reused across phases
  const int tid  = threadIdx.x;
  const int lane = tid & 63;
  const int w    = __builtin_amdgcn_readfirstlane(tid >> 6);
  const int gw   = blockIdx.x * 4 + w;  // 512 blocks * 4 waves = 2048 waves

  // ---- phase A staging: W1s@0, W1v@4096, W2s@8192, W2v@12288 ----
  {
    float4* l4 = (float4*)lds;
    #pragma unroll
    for (int i = 0; i < 4; ++i) {
      l4[        i*256 + tid] = ((const float4*)W1s)[i*256 + tid];
      l4[1024 +  i*256 + tid] = ((const float4*)W1v)[i*256 + tid];
      l4[2048 +  i*256 + tid] = ((const float4*)W2s)[i*256 + tid];
      l4[3072 +  i*256 + tid] = ((const float4*)W2v)[i*256 + tid];
    }
  }
  __syncthreads();

  // ---- phase A: l1s/l1v (S) and l2s/l2v (R), lane = v ----
  for (int n = gw; n < NN; n += 2048) {
    const float* nrow = nf + (size_t)n * 256;
    float a1s=0.f, a2s=0.f, a1v0=0.f, a1v1=0.f, a1v2=0.f, a2v0=0.f, a2v1=0.f, a2v2=0.f;
    #pragma unroll 4
    for (int u = 0; u < 64; ++u) {
      const float su  = nrow[u];            // wave-uniform -> s_load
      const float nv0 = nrow[64 + u*3];
      const float nv1 = nrow[65 + u*3];
      const float nv2 = nrow[66 + u*3];
      const float w1s = lds[         u*64 + lane];
      const float w1v = lds[ 4096 +  u*64 + lane];
      const float w2s = lds[ 8192 +  u*64 + lane];
      const float w2v = lds[12288 +  u*64 + lane];
      a1s  += su *w1s;  a2s  += su *w2s;
      a1v0 += nv0*w1v;  a1v1 += nv1*w1v;  a1v2 += nv2*w1v;
      a2v0 += nv0*w2v;  a2v1 += nv1*w2v;  a2v2 += nv2*w2v;
    }
    const size_t rec = (size_t)n * 768;
    const int qo = (lane>>2)*48 + (lane&3);   // quad-major slot for v=lane
    wsS[rec+qo]    = a1s *QINV;
    wsS[rec+qo+4]  = a1v0*QINV;
    wsS[rec+qo+8]  = a1v1*QINV;
    wsS[rec+qo+12] = a1v2*QINV;
    wsR[rec+qo]    = a2s *QINV;
    wsR[rec+qo+4]  = a2v0*QINV;
    wsR[rec+qo+8]  = a2v1*QINV;
    wsR[rec+qo+12] = a2v2*QINV;
  }
  __syncthreads();

  // ---- phase B staging (transposed Wv* for conflict-free per-U reads) ----
  // T_vss@0, T_vsv@2048, T_vrs@4096, T_vrv@6144 (each [up][128])
  // Wfs0@8192, Wfs1@8448, Wfr0@8704, Wfr1@8960 (row-major, broadcast)
  // T_msv@9216, T_mvs@10240 (each [v][64])
  for (int i = tid; i < 2048; i += 256) {
    const int U = i >> 4, up = i & 15;
    lds[       up*128 + U] = Wvss[i];
    lds[2048 + up*128 + U] = Wvsv[i];
    lds[4096 + up*128 + U] = Wvrs[i];
    lds[6144 + up*128 + U] = Wvrv[i];
  }
  { lds[8192+tid]=Wfs0[tid]; lds[8448+tid]=Wfs1[tid]; lds[8704+tid]=Wfr0[tid]; lds[8960+tid]=Wfr1[tid]; }
  for (int i = tid; i < 1024; i += 256) {
    const int u = i >> 4, v = i & 15;
    lds[ 9216 + v*64 + u] = Wmsv[i];
    lds[10240 + v*64 + u] = Wmvs[i];
  }
  __syncthreads();

  // ---- phase B: q/r tables (lane = U within half) + mp1 (lane = u) ----
  for (int n = gw; n < NN; n += 2048) {
    const float* fr = ff + (size_t)n * 64;
    float fs[16], fv[48];
    #pragma unroll
    for (int j = 0; j < 16; ++j) fs[j] = rfl(fr[j]);      // force SGPR
    #pragma unroll
    for (int j = 0; j < 48; ++j) fv[j] = rfl(fr[16+j]);

    float gsA[16], gsB[16], gvA[48], gvB[48];
    #pragma unroll
    for (int up = 0; up < 16; ++up) {
      float sA=0.f,sB=0.f,a0=0.f,a1=0.f,a2=0.f,b0=0.f,b1=0.f,b2=0.f;
      #pragma unroll
      for (int v = 0; v < 16; ++v) {
        const float w0 = lds[8192+up*16+v];
        const float w1 = lds[8448+up*16+v];
        const float w2 = lds[8704+up*16+v];
        const float w3 = lds[8960+up*16+v];
        sA += w0*fs[v];                 sB += w2*fs[v];
        a0 += w1*fv[v*3]; a1 += w1*fv[v*3+1]; a2 += w1*fv[v*3+2];
        b0 += w3*fv[v*3]; b1 += w3*fv[v*3+1]; b2 += w3*fv[v*3+2];
      }
      gsA[up]=sA; gsB[up]=sB;
      gvA[up*3]=a0; gvA[up*3+1]=a1; gvA[up*3+2]=a2;
      gvB[up*3]=b0; gvB[up*3+1]=b1; gvB[up*3+2]=b2;
    }

    const size_t rec = (size_t)n * 768;
    #pragma unroll
    for (int hf = 0; hf < 2; ++hf) {
      const int U = hf*64 + lane;
      float qa=0.f,qb=0.f,r0=0.f,r1=0.f,r2=0.f,s0=0.f,s1=0.f,s2=0.f;
      #pragma unroll
      for (int up = 0; up < 16; ++up) {
        const float tvs = lds[       up*128 + U];
        const float tvv = lds[2048 + up*128 + U];
        const float trs = lds[4096 + up*128 + U];
        const float trv = lds[6144 + up*128 + U];
        qa += tvs*gsA[up];  qb += trs*gsB[up];
        r0 += tvv*gvA[up*3]; r1 += tvv*gvA[up*3+1]; r2 += tvv*gvA[up*3+2];
        s0 += trv*gvB[up*3]; s1 += trv*gvB[up*3+1]; s2 += trv*gvB[up*3+2];
      }
      const int base = (lane>>2)*48 + (lane&3);
      const float qsc = hf ? ISQ3 : 1.f;
      wsS[rec + base + 16 + hf*4] = qa*qsc;
      wsR[rec + base + 16 + hf*4] = qb*qsc;
      const int ro = base + 24 + hf*12;
      wsS[rec+ro]   = r0*ISQ3; wsS[rec+ro+4] = r1*ISQ3; wsS[rec+ro+8] = r2*ISQ3;
      wsR[rec+ro]   = s0*ISQ3; wsR[rec+ro+4] = s1*ISQ3; wsR[rec+ro+8] = s2*ISQ3;
    }

    // mp1 (mp0 is dead: overwritten by charges)
    const float su  = nf[(size_t)n*256 + lane];
    const float nv0 = nf[(size_t)n*256 + 64 + lane*3];
    const float nv1 = nf[(size_t)n*256 + 64 + lane*3 + 1];
    const float nv2 = nf[(size_t)n*256 + 64 + lane*3 + 2];
    float t2=0.f, g0=0.f, g1=0.f, g2=0.f;
    #pragma unroll
    for (int v = 0; v < 16; ++v) {
      const float tm = lds[10240 + v*64 + lane];  // T_mvs
      const float ts = lds[ 9216 + v*64 + lane];  // T_msv
      t2 += tm*fs[v];
      g0 += ts*fv[v*3]; g1 += ts*fv[v*3+1]; g2 += ts*fv[v*3+2];
    }
    float r0 = nv0*t2 + su*g0;
    float r1 = nv1*t2 + su*g1;
    float r2 = nv2*t2 + su*g2;
    #pragma unroll
    for (int off = 32; off; off >>= 1) {
      r0 += __shfl_xor(r0, off, 64);
      r1 += __shfl_xor(r1, off, 64);
      r2 += __shfl_xor(r2, off, 64);
    }
    if (lane == 0) {
      float4 o; o.x = 0.f; o.y = MPSC*r0; o.z = MPSC*r1; o.w = MPSC*r2;
      *(float4*)(out + (size_t)n*4) = o;
    }
  }
}

// ------- edge kernel: h in regs, W1-3 in LDS (broadcast), W4 scalar slices -------
__global__ __launch_bounds__(256, 2) void edge_kernel(
    const float* __restrict__ ea, const float* __restrict__ efe,
    const int* __restrict__ eidx,
    const float* __restrict__ mw1, const float* __restrict__ mw2,
    const float* __restrict__ mw3, const float* __restrict__ mw4,
    const float* __restrict__ wsS, const float* __restrict__ wsR,
    float* __restrict__ out)
{
  __shared__ float lw[8704];   // lw1@0 (512), lw2@512 (4096), lw3@4608 (4096) = 34 KB
  const int tid = threadIdx.x;
  const int e = blockIdx.x * 256 + tid;      // grid = 625*256 = NE exactly
  const int s = eidx[e];
  const int r = eidx[NE + e];
  const float4 y = ld4(ea + (size_t)e*4);
  float ef[8];
  {
    const float4 a = ld4(efe + (size_t)e*8);
    const float4 b = ld4(efe + (size_t)e*8 + 4);
    ef[0]=a.x; ef[1]=a.y; ef[2]=a.z; ef[3]=a.w;
    ef[4]=b.x; ef[5]=b.y; ef[6]=b.z; ef[7]=b.w;
  }
  {
    float4* l4 = (float4*)lw;
    if (tid < 128) l4[tid] = ((const float4*)mw1)[tid];
    #pragma unroll
    for (int i = 0; i < 4; ++i) l4[ 128 + i*256 + tid] = ((const float4*)mw2)[i*256 + tid];
    #pragma unroll
    for (int i = 0; i < 4; ++i) l4[1152 + i*256 + tid] = ((const float4*)mw3)[i*256 + tid];
  }
  __syncthreads();

  float h[64], acc[64];
  // ---- L1: 8 -> 64 (lw1 broadcast) ----
  #pragma unroll
  for (int j = 0; j < 64; ++j) acc[j] = 0.f;
  #pragma unroll
  for (int k = 0; k < 8; ++k) {
    #pragma unroll
    for (int q = 0; q < 16; ++q) {
      const float4 wv = *(const float4*)(lw + k*64 + q*4);
      acc[q*4]   += ef[k]*wv.x; acc[q*4+1] += ef[k]*wv.y;
      acc[q*4+2] += ef[k]*wv.z; acc[q*4+3] += ef[k]*wv.w;
    }
  }
  #pragma unroll
  for (int j = 0; j < 64; ++j) h[j] = sil(acc[j]*INV8);

  // ---- L2: 64 -> 64 (lw2 broadcast) ----
  #pragma unroll
  for (int j = 0; j < 64; ++j) acc[j] = 0.f;
  #pragma unroll 64
  for (int k = 0; k < 64; ++k) {
    const float hk = h[k];
    #pragma unroll
    for (int q = 0; q < 16; ++q) {
      const float4 wv = *(const float4*)(lw + 512 + k*64 + q*4);
      acc[q*4]   += hk*wv.x; acc[q*4+1] += hk*wv.y;
      acc[q*4+2] += hk*wv.z; acc[q*4+3] += hk*wv.w;
    }
  }
  #pragma unroll
  for (int j = 0; j < 64; ++j) h[j] = sil(acc[j]*QINV);

  // ---- L3: 64 -> 64 (lw3 broadcast) ----
  #pragma unroll
  for (int j = 0; j < 64; ++j) acc[j] = 0.f;
  #pragma unroll 64
  for (int k = 0; k < 64; ++k) {
    const float hk = h[k];
    #pragma unroll
    for (int q = 0; q < 16; ++q) {
      const float4 wv = *(const float4*)(lw + 4608 + k*64 + q*4);
      acc[q*4]   += hk*wv.x; acc[q*4+1] += hk*wv.y;
      acc[q*4+2] += hk*wv.z; acc[q*4+3] += hk*wv.w;
    }
  }
  #pragma unroll
  for (int j = 0; j < 64; ++j) h[j] = sil(acc[j]*QINV);

  // ---- L4 + combine + contraction, per u-quad ----
  float accS = 0.f, accR = 0.f;
  const float* Sb = wsS + (size_t)s*768;
  const float* Rb = wsR + (size_t)r*768;
  for (int uq = 0; uq < 16; ++uq) {
    const float* Sr = Sb + uq*48;
    const float* Rr = Rb + uq*48;
    // batch 1 gathers (b-terms) — issued ahead of the wq block
    const float4 bsS=ld4(Sr+0), sv0=ld4(Sr+4), sv1=ld4(Sr+8), sv2=ld4(Sr+12);
    const float4 bsR=ld4(Rr+0), rv0=ld4(Rr+4), rv1=ld4(Rr+8), rv2=ld4(Rr+12);

    float wq[16];
    #pragma unroll
    for (int j = 0; j < 16; ++j) wq[j] = 0.f;
    const float* w4b = mw4 + uq*4;              // wave-uniform -> scalar loads
    #pragma unroll 64
    for (int k = 0; k < 64; ++k) {
      const float hk = h[k];
      const float4 c0 = ld4(w4b + k*256);
      const float4 c1 = ld4(w4b + k*256 + 64);
      const float4 c2 = ld4(w4b + k*256 + 128);
      const float4 c3 = ld4(w4b + k*256 + 192);
      wq[0] +=hk*c0.x; wq[1] +=hk*c0.y; wq[2] +=hk*c0.z; wq[3] +=hk*c0.w;
      wq[4] +=hk*c1.x; wq[5] +=hk*c1.y; wq[6] +=hk*c1.z; wq[7] +=hk*c1.w;
      wq[8] +=hk*c2.x; wq[9] +=hk*c2.y; wq[10]+=hk*c2.z; wq[11]+=hk*c2.w;
      wq[12]+=hk*c3.x; wq[13]+=hk*c3.y; wq[14]+=hk*c3.z; wq[15]+=hk*c3.w;
    }

    // batch 2 gathers (q/r tables)
    const float4 qa0=ld4(Sr+16), qa1=ld4(Sr+20);
    const float4 ra00=ld4(Sr+24),ra01=ld4(Sr+28),ra02=ld4(Sr+32);
    const float4 ra10=ld4(Sr+36),ra11=ld4(Sr+40),ra12=ld4(Sr+44);
    const float4 qb0=ld4(Rr+16), qb1=ld4(Rr+20);
    const float4 rb00=ld4(Rr+24),rb01=ld4(Rr+28),rb02=ld4(Rr+32);
    const float4 rb10=ld4(Rr+36),rb11=ld4(Rr+40),rb12=ld4(Rr+44);

    #pragma unroll
    for (int d = 0; d < 4; ++d) {
      const float bs = C4(bsS,d) + C4(bsR,d);
      const float b0 = C4(sv0,d) + C4(rv0,d);
      const float b1 = C4(sv1,d) + C4(rv1,d);
      const float b2 = C4(sv2,d) + C4(rv2,d);
      const float bvy = b0*y.y + b1*y.z + b2*y.w;
      const float m0 = wq[d]    * bs * y.x;
      const float m1 = wq[4+d]  * bvy;
      const float m2 = wq[8+d]  * bs;
      const float m3 = wq[12+d] * y.x;
      accS += m0*C4(qa0,d) + m1*C4(qa1,d)
            + m2*(y.y*C4(ra00,d) + y.z*C4(ra01,d) + y.w*C4(ra02,d))
            + m3*(b0*C4(ra10,d) + b1*C4(ra11,d) + b2*C4(ra12,d));
      accR += m0*C4(qb0,d) + m1*C4(qb1,d)
            + m2*(y.y*C4(rb00,d) + y.z*C4(rb01,d) + y.w*C4(rb02,d))
            + m3*(b0*C4(rb10,d) + b1*C4(rb11,d) + b2*C4(rb12,d));
    }
  }
  const float pj = FINALS * (accS + accR);
  out[NN*4 + e] = pj;
  atomicAdd(out + (size_t)r*4, pj);
  atomicAdd(out + (size_t)s*4, -pj);
}

extern "C" void kernel_launch(void* const* d_in, const int* in_sizes, int n_in,
                              void* d_out, int out_size, void* d_ws, size_t ws_size,
                              hipStream_t stream) {
  (void)in_sizes; (void)n_in; (void)out_size; (void)ws_size;
  const float* node_feats  = (const float*)d_in[1];
  const float* edge_attrs  = (const float*)d_in[2];
  const float* edge_feats  = (const float*)d_in[3];
  const float* field_feats = (const float*)d_in[4];
  const int*   edge_index  = (const int*)  d_in[5];
  const float* W1s  = (const float*)d_in[6];
  const float* W1v  = (const float*)d_in[7];
  const float* W2s  = (const float*)d_in[8];
  const float* W2v  = (const float*)d_in[9];
  const float* mw1  = (const float*)d_in[10];
  const float* mw2  = (const float*)d_in[11];
  const float* mw3  = (const float*)d_in[12];
  const float* mw4  = (const float*)d_in[13];
  const float* Wvss = (const float*)d_in[14];
  const float* Wvsv = (const float*)d_in[15];
  const float* Wvrs = (const float*)d_in[16];
  const float* Wvrv = (const float*)d_in[17];
  const float* Wfs0 = (const float*)d_in[18];
  const float* Wfs1 = (const float*)d_in[19];
  const float* Wfr0 = (const float*)d_in[20];
  const float* Wfr1 = (const float*)d_in[21];
  // d_in[22]/d_in[23] (Wmp_ss/Wmp_vv) feed only mp0, which charges overwrite -> dead.
  const float* Wmsv = (const float*)d_in[24];
  const float* Wmvs = (const float*)d_in[25];

  float* out = (float*)d_out;
  float* wsS = (float*)d_ws;                 // 10000*768 floats
  float* wsR = wsS + (size_t)NN*768;         // total 61.44 MB

  hipLaunchKernelGGL(node_kernel, dim3(512), dim3(256), 0, stream,
      node_feats, field_feats, W1s, W1v, W2s, W2v, Wvss, Wvsv, Wvrs, Wvrv,
      Wfs0, Wfs1, Wfr0, Wfr1, Wmsv, Wmvs, wsS, wsR, out);
  hipLaunchKernelGGL(edge_kernel, dim3(625), dim3(256), 0, stream,
      edge_attrs, edge_feats, edge_index, mw1, mw2, mw3, mw4, wsS, wsR, out);
}

// Round 6
// 440.997 us; speedup vs baseline: 1.7915x; 1.7915x over previous
//
#include <hip/hip_runtime.h>

#define NN 10000
#define NE 160000

#define INV8   0.35355339059327373f   // 1/sqrt(8)
#define QINV   0.125f                 // 1/sqrt(64)
#define GAIN   1.679177f
#define ISQ3   0.57735026918962576f   // 1/sqrt(3)
#define FINALS 4.8828125e-5f          // 0.1 * (1/sqrt(512)) * (1/sqrt(128)) * 0.125(=tp_w's 1/sqrt64)
#define MPSC   2.2097086912079612e-4f // 0.01 / sqrt(2048)

typedef __attribute__((ext_vector_type(8))) short bf16x8;
typedef __attribute__((ext_vector_type(4))) float f32x4;

__device__ __forceinline__ float4 ld4(const float* p){ return *(const float4*)p; }
__device__ __forceinline__ void st4f(float* p, float a, float b, float c, float d){
  float4 t; t.x=a; t.y=b; t.z=c; t.w=d; *(float4*)p = t;
}
__device__ __forceinline__ float sil(float x){ return x*GAIN/(1.f+__expf(-x)); }
__device__ __forceinline__ unsigned short f2b(float f){   // f32 -> bf16 RNE
  unsigned u = __float_as_uint(f);
  return (unsigned short)((u + 0x7FFFu + ((u>>16)&1u)) >> 16);
}
__device__ __forceinline__ float b2f(unsigned short b){
  return __uint_as_float(((unsigned)b) << 16);
}
#define C4(v,i) (((const float*)&(v))[i])

// =================== MLP kernel: MFMA bf16, 128 edges/block ===================
// NOTE: L4 output is stored RAW (h3 @ mw4, no 1/sqrt64) — that scale lives in
// combine's FINALS (round-2 convention). Double-applying it was the round-4/5 bug.
__global__ __launch_bounds__(256, 2) void mlp_kernel(
    const float* __restrict__ efe,
    const float* __restrict__ mw1, const float* __restrict__ mw2,
    const float* __restrict__ mw3, const float* __restrict__ mw4,
    unsigned short* __restrict__ wout)
{
  __shared__ __align__(16) unsigned short H  [128*64];
  __shared__ __align__(16) unsigned short W1t[64*32];
  __shared__ __align__(16) unsigned short W2t[64*64];
  __shared__ __align__(16) unsigned short W3t[64*64];
  __shared__ __align__(16) unsigned short W4q[64*64];
  const int tid = threadIdx.x;
  const int wv  = tid >> 6;
  const int l   = tid & 63;
  const int eb  = blockIdx.x * 128;

  #pragma unroll
  for (int it = 0; it < 16; ++it) {
    const int i = tid + 256*it, e = i >> 5, k = i & 31;
    H[e*64 + (k ^ ((e&7)<<3))] = (k < 8) ? f2b(efe[(size_t)(eb+e)*8 + k]) : 0;
  }
  #pragma unroll
  for (int it = 0; it < 8; ++it) {
    const int i = tid + 256*it, n = i >> 5, k = i & 31;
    W1t[n*32 + (k ^ ((n&3)<<3))] = (k < 8) ? f2b(mw1[k*64 + n]) : 0;
  }
  #pragma unroll
  for (int it = 0; it < 16; ++it) {
    const int i = tid + 256*it, k = i >> 6, n = i & 63;
    W2t[n*64 + (k ^ ((n&7)<<3))] = f2b(mw2[k*64 + n]);
    W3t[n*64 + (k ^ ((n&7)<<3))] = f2b(mw3[k*64 + n]);
  }
  __syncthreads();

  const int arow = l & 15;
  const int koff = (l >> 4) * 8;

  {
    bf16x8 a[8];
    #pragma unroll
    for (int mf = 0; mf < 8; ++mf) {
      const int e = mf*16 + arow;
      a[mf] = *(const bf16x8*)&H[e*64 + (koff ^ ((e&7)<<3))];
    }
    const int n = wv*16 + arow;
    const bf16x8 b = *(const bf16x8*)&W1t[n*32 + (koff ^ ((n&3)<<3))];
    __syncthreads();
    f32x4 acc[8];
    #pragma unroll
    for (int mf = 0; mf < 8; ++mf) {
      acc[mf] = (f32x4){0.f,0.f,0.f,0.f};
      acc[mf] = __builtin_amdgcn_mfma_f32_16x16x32_bf16(a[mf], b, acc[mf], 0, 0, 0);
    }
    #pragma unroll
    for (int mf = 0; mf < 8; ++mf)
      #pragma unroll
      for (int rg = 0; rg < 4; ++rg) {
        const int e = mf*16 + (l>>4)*4 + rg, j = wv*16 + arow;
        H[e*64 + (j ^ ((e&7)<<3))] = f2b(sil(acc[mf][rg]*INV8));
      }
    __syncthreads();
  }

  const unsigned short* Wt[2] = { W2t, W3t };
  #pragma unroll
  for (int ly = 0; ly < 2; ++ly) {
    bf16x8 a[16];
    #pragma unroll
    for (int mf = 0; mf < 8; ++mf)
      #pragma unroll
      for (int ks = 0; ks < 2; ++ks) {
        const int e = mf*16 + arow, kb = ks*32 + koff;
        a[mf*2+ks] = *(const bf16x8*)&H[e*64 + (kb ^ ((e&7)<<3))];
      }
    const int n = wv*16 + arow;
    bf16x8 b0, b1;
    {
      const int kb0 = koff, kb1 = 32 + koff;
      b0 = *(const bf16x8*)&Wt[ly][n*64 + (kb0 ^ ((n&7)<<3))];
      b1 = *(const bf16x8*)&Wt[ly][n*64 + (kb1 ^ ((n&7)<<3))];
    }
    __syncthreads();
    f32x4 acc[8];
    #pragma unroll
    for (int mf = 0; mf < 8; ++mf) {
      acc[mf] = (f32x4){0.f,0.f,0.f,0.f};
      acc[mf] = __builtin_amdgcn_mfma_f32_16x16x32_bf16(a[mf*2+0], b0, acc[mf], 0, 0, 0);
      acc[mf] = __builtin_amdgcn_mfma_f32_16x16x32_bf16(a[mf*2+1], b1, acc[mf], 0, 0, 0);
    }
    #pragma unroll
    for (int mf = 0; mf < 8; ++mf)
      #pragma unroll
      for (int rg = 0; rg < 4; ++rg) {
        const int e = mf*16 + (l>>4)*4 + rg, j = wv*16 + arow;
        H[e*64 + (j ^ ((e&7)<<3))] = f2b(sil(acc[mf][rg]*QINV));
      }
    __syncthreads();
  }

  bf16x8 a4[16];
  #pragma unroll
  for (int mf = 0; mf < 8; ++mf)
    #pragma unroll
    for (int ks = 0; ks < 2; ++ks) {
      const int e = mf*16 + arow, kb = ks*32 + koff;
      a4[mf*2+ks] = *(const bf16x8*)&H[e*64 + (kb ^ ((e&7)<<3))];
    }

  for (int q = 0; q < 4; ++q) {
    #pragma unroll
    for (int it = 0; it < 16; ++it) {
      const int i = tid + 256*it, k = i >> 6, nn = i & 63;
      W4q[nn*64 + (k ^ ((nn&7)<<3))] = f2b(mw4[k*256 + q*64 + nn]);
    }
    __syncthreads();

    const int n = wv*16 + arow;
    const bf16x8 b0 = *(const bf16x8*)&W4q[n*64 + ((koff     ) ^ ((n&7)<<3))];
    const bf16x8 b1 = *(const bf16x8*)&W4q[n*64 + ((32 + koff) ^ ((n&7)<<3))];
    f32x4 acc[8];
    #pragma unroll
    for (int mf = 0; mf < 8; ++mf) {
      acc[mf] = (f32x4){0.f,0.f,0.f,0.f};
      acc[mf] = __builtin_amdgcn_mfma_f32_16x16x32_bf16(a4[mf*2+0], b0, acc[mf], 0, 0, 0);
      acc[mf] = __builtin_amdgcn_mfma_f32_16x16x32_bf16(a4[mf*2+1], b1, acc[mf], 0, 0, 0);
    }
    #pragma unroll
    for (int mf = 0; mf < 8; ++mf)
      #pragma unroll
      for (int rg = 0; rg < 4; ++rg) {
        const int e = mf*16 + (l>>4)*4 + rg, j = wv*16 + arow;
        H[e*64 + (j ^ ((e&7)<<3))] = f2b(acc[mf][rg]);   // RAW: 1/sqrt64 lives in FINALS
      }
    __syncthreads();

    {
      const int e  = tid & 127;
      const int jh = tid >> 7;
      #pragma unroll
      for (int g = 0; g < 4; ++g) {
        const int jb = jh*32 + g*8;
        const bf16x8 vw = *(const bf16x8*)&H[e*64 + (jb ^ ((e&7)<<3))];
        #pragma unroll
        for (int d = 0; d < 8; ++d)
          wout[(size_t)(q*64 + jb + d)*NE + eb + e] = ((const unsigned short*)&vw)[d];
      }
    }
  }
}

// =================== node kernel (round-2 verbatim, known-good) ===================
__global__ __launch_bounds__(256) void node_kernel(
    const float* __restrict__ nf, const float* __restrict__ ff,
    const float* __restrict__ W1s, const float* __restrict__ W1v,
    const float* __restrict__ W2s, const float* __restrict__ W2v,
    const float* __restrict__ Wvss, const float* __restrict__ Wvsv,
    const float* __restrict__ Wvrs, const float* __restrict__ Wvrv,
    const float* __restrict__ Wfs0, const float* __restrict__ Wfs1,
    const float* __restrict__ Wfr0, const float* __restrict__ Wfr1,
    const float* __restrict__ Wmsv, const float* __restrict__ Wmvs,
    float* __restrict__ wsS, float* __restrict__ wsR,
    float* __restrict__ out)
{
  const int lane = threadIdx.x & 63;
  const int Wid  = blockIdx.x * 4 + (threadIdx.x >> 6);
  const int p    = __builtin_amdgcn_readfirstlane(Wid & 7);
  const int grp  = __builtin_amdgcn_readfirstlane(Wid >> 3);
  const int n = grp * 64 + lane;
  if (n >= NN) return;
  const float* nrow = nf + (size_t)n * 256;
  const int vb = p * 8;
  const size_t rec = (size_t)n * 768;

  float a1s[8], a2s[8], a1v[3][8], a2v[3][8], t1[16];
  #pragma unroll
  for (int j = 0; j < 8; ++j){ a1s[j]=0.f; a2s[j]=0.f;
    a1v[0][j]=0.f; a1v[1][j]=0.f; a1v[2][j]=0.f;
    a2v[0][j]=0.f; a2v[1][j]=0.f; a2v[2][j]=0.f; }
  #pragma unroll
  for (int j = 0; j < 16; ++j) t1[j]=0.f;

  for (int u = 0; u < 64; ++u) {
    const float su  = nrow[u];
    const float nv0 = nrow[64+u*3+0];
    const float nv1 = nrow[64+u*3+1];
    const float nv2 = nrow[64+u*3+2];
    const float4 s1a = ld4(W1s+u*64+vb), s1b = ld4(W1s+u*64+vb+4);
    const float4 s2a = ld4(W2s+u*64+vb), s2b = ld4(W2s+u*64+vb+4);
    const float4 v1a = ld4(W1v+u*64+vb), v1b = ld4(W1v+u*64+vb+4);
    const float4 v2a = ld4(W2v+u*64+vb), v2b = ld4(W2v+u*64+vb+4);
    #pragma unroll
    for (int d = 0; d < 4; ++d) {
      a1s[d]     += su*C4(s1a,d);  a1s[4+d]     += su*C4(s1b,d);
      a2s[d]     += su*C4(s2a,d);  a2s[4+d]     += su*C4(s2b,d);
      a1v[0][d]  += nv0*C4(v1a,d); a1v[0][4+d]  += nv0*C4(v1b,d);
      a1v[1][d]  += nv1*C4(v1a,d); a1v[1][4+d]  += nv1*C4(v1b,d);
      a1v[2][d]  += nv2*C4(v1a,d); a1v[2][4+d]  += nv2*C4(v1b,d);
      a2v[0][d]  += nv0*C4(v2a,d); a2v[0][4+d]  += nv0*C4(v2b,d);
      a2v[1][d]  += nv1*C4(v2a,d); a2v[1][4+d]  += nv1*C4(v2b,d);
      a2v[2][d]  += nv2*C4(v2a,d); a2v[2][4+d]  += nv2*C4(v2b,d);
    }
    if (p == 0) {
      #pragma unroll
      for (int q = 0; q < 4; ++q) {
        const float4 m = ld4(Wmsv + u*16 + q*4);
        t1[q*4]   += su*m.x; t1[q*4+1] += su*m.y;
        t1[q*4+2] += su*m.z; t1[q*4+3] += su*m.w;
      }
    }
  }
  #pragma unroll
  for (int hh = 0; hh < 2; ++hh) {
    const int uq = 2*p + hh, o = hh*4;
    float* S = wsS + rec + uq*48;
    float* R = wsR + rec + uq*48;
    st4f(S+0,  a1s[o]*QINV, a1s[o+1]*QINV, a1s[o+2]*QINV, a1s[o+3]*QINV);
    st4f(S+4,  a1v[0][o]*QINV, a1v[0][o+1]*QINV, a1v[0][o+2]*QINV, a1v[0][o+3]*QINV);
    st4f(S+8,  a1v[1][o]*QINV, a1v[1][o+1]*QINV, a1v[1][o+2]*QINV, a1v[1][o+3]*QINV);
    st4f(S+12, a1v[2][o]*QINV, a1v[2][o+1]*QINV, a1v[2][o+2]*QINV, a1v[2][o+3]*QINV);
    st4f(R+0,  a2s[o]*QINV, a2s[o+1]*QINV, a2s[o+2]*QINV, a2s[o+3]*QINV);
    st4f(R+4,  a2v[0][o]*QINV, a2v[0][o+1]*QINV, a2v[0][o+2]*QINV, a2v[0][o+3]*QINV);
    st4f(R+8,  a2v[1][o]*QINV, a2v[1][o+1]*QINV, a2v[1][o+2]*QINV, a2v[1][o+3]*QINV);
    st4f(R+12, a2v[2][o]*QINV, a2v[2][o+1]*QINV, a2v[2][o+2]*QINV, a2v[2][o+3]*QINV);
  }

  float fsv[16], fvv[48];
  {
    const float* fr = ff + (size_t)n*64;
    #pragma unroll
    for (int q = 0; q < 4; ++q) {
      const float4 t = ld4(fr + q*4);
      fsv[q*4]=t.x; fsv[q*4+1]=t.y; fsv[q*4+2]=t.z; fsv[q*4+3]=t.w;
    }
    #pragma unroll
    for (int q = 0; q < 12; ++q) {
      const float4 t = ld4(fr + 16 + q*4);
      fvv[q*4]=t.x; fvv[q*4+1]=t.y; fvv[q*4+2]=t.z; fvv[q*4+3]=t.w;
    }
  }

  if (p == 0) {
    float m0=0.f, m1=0.f, m2=0.f;
    #pragma unroll
    for (int v = 0; v < 16; ++v) {
      m0 += t1[v]*fvv[v*3]; m1 += t1[v]*fvv[v*3+1]; m2 += t1[v]*fvv[v*3+2];
    }
    for (int u = 0; u < 64; ++u) {
      float t2 = 0.f;
      #pragma unroll
      for (int q = 0; q < 4; ++q) {
        const float4 w = ld4(Wmvs + u*16 + q*4);
        t2 += w.x*fsv[q*4] + w.y*fsv[q*4+1] + w.z*fsv[q*4+2] + w.w*fsv[q*4+3];
      }
      m0 += nrow[64+u*3+0]*t2;
      m1 += nrow[64+u*3+1]*t2;
      m2 += nrow[64+u*3+2]*t2;
    }
    float* o = out + (size_t)n*4;
    o[0] = 0.f;
    o[1] = MPSC*m0; o[2] = MPSC*m1; o[3] = MPSC*m2;
  }

  float gsA[16], gsB[16], gvA[48], gvB[48];
  #pragma unroll
  for (int up = 0; up < 16; ++up) {
    float sA=0.f,sB=0.f,vA0=0.f,vA1=0.f,vA2=0.f,vB0=0.f,vB1=0.f,vB2=0.f;
    #pragma unroll
    for (int q = 0; q < 4; ++q) {
      const float4 w0 = ld4(Wfs0 + up*16 + q*4);
      const float4 w1 = ld4(Wfs1 + up*16 + q*4);
      const float4 w2 = ld4(Wfr0 + up*16 + q*4);
      const float4 w3 = ld4(Wfr1 + up*16 + q*4);
      #pragma unroll
      for (int d = 0; d < 4; ++d) {
        const int v = q*4+d;
        sA  += C4(w0,d)*fsv[v];
        sB  += C4(w2,d)*fsv[v];
        vA0 += C4(w1,d)*fvv[v*3]; vA1 += C4(w1,d)*fvv[v*3+1]; vA2 += C4(w1,d)*fvv[v*3+2];
        vB0 += C4(w3,d)*fvv[v*3]; vB1 += C4(w3,d)*fvv[v*3+1]; vB2 += C4(w3,d)*fvv[v*3+2];
      }
    }
    gsA[up]=sA; gsB[up]=sB;
    gvA[up*3]=vA0; gvA[up*3+1]=vA1; gvA[up*3+2]=vA2;
    gvB[up*3]=vB0; gvB[up*3+1]=vB1; gvB[up*3+2]=vB2;
  }

  #pragma unroll
  for (int tq = 0; tq < 4; ++tq) {
    float qa[4], qb[4], ra[3][4], rb[3][4];
    #pragma unroll
    for (int d = 0; d < 4; ++d) {
      const int U = p*16 + tq*4 + d;
      float aq=0.f,bq=0.f,a0=0.f,a1=0.f,a2=0.f,b0=0.f,b1=0.f,b2=0.f;
      #pragma unroll
      for (int q = 0; q < 4; ++q) {
        const float4 ws_ = ld4(Wvss + U*16 + q*4);
        const float4 wr_ = ld4(Wvrs + U*16 + q*4);
        const float4 wv_ = ld4(Wvsv + U*16 + q*4);
        const float4 wu_ = ld4(Wvrv + U*16 + q*4);
        #pragma unroll
        for (int dd = 0; dd < 4; ++dd) {
          const int up = q*4+dd;
          aq += C4(ws_,dd)*gsA[up];
          bq += C4(wr_,dd)*gsB[up];
          a0 += C4(wv_,dd)*gvA[up*3]; a1 += C4(wv_,dd)*gvA[up*3+1]; a2 += C4(wv_,dd)*gvA[up*3+2];
          b0 += C4(wu_,dd)*gvB[up*3]; b1 += C4(wu_,dd)*gvB[up*3+1]; b2 += C4(wu_,dd)*gvB[up*3+2];
        }
      }
      qa[d]=aq; qb[d]=bq;
      ra[0][d]=a0*ISQ3; ra[1][d]=a1*ISQ3; ra[2][d]=a2*ISQ3;
      rb[0][d]=b0*ISQ3; rb[1][d]=b1*ISQ3; rb[2][d]=b2*ISQ3;
    }
    if (p < 4) {
      const int uq = p*4 + tq;
      float* S = wsS + rec + uq*48;
      float* R = wsR + rec + uq*48;
      st4f(S+16, qa[0],qa[1],qa[2],qa[3]);
      st4f(S+24, ra[0][0],ra[0][1],ra[0][2],ra[0][3]);
      st4f(S+28, ra[1][0],ra[1][1],ra[1][2],ra[1][3]);
      st4f(S+32, ra[2][0],ra[2][1],ra[2][2],ra[2][3]);
      st4f(R+16, qb[0],qb[1],qb[2],qb[3]);
      st4f(R+24, rb[0][0],rb[0][1],rb[0][2],rb[0][3]);
      st4f(R+28, rb[1][0],rb[1][1],rb[1][2],rb[1][3]);
      st4f(R+32, rb[2][0],rb[2][1],rb[2][2],rb[2][3]);
    } else {
      const int uq = (p-4)*4 + tq;
      float* S = wsS + rec + uq*48;
      float* R = wsR + rec + uq*48;
      st4f(S+20, qa[0]*ISQ3,qa[1]*ISQ3,qa[2]*ISQ3,qa[3]*ISQ3);
      st4f(S+36, ra[0][0],ra[0][1],ra[0][2],ra[0][3]);
      st4f(S+40, ra[1][0],ra[1][1],ra[1][2],ra[1][3]);
      st4f(S+44, ra[2][0],ra[2][1],ra[2][2],ra[2][3]);
      st4f(R+20, qb[0]*ISQ3,qb[1]*ISQ3,qb[2]*ISQ3,qb[3]*ISQ3);
      st4f(R+36, rb[0][0],rb[0][1],rb[0][2],rb[0][3]);
      st4f(R+40, rb[1][0],rb[1][1],rb[1][2],rb[1][3]);
      st4f(R+44, rb[2][0],rb[2][1],rb[2][2],rb[2][3]);
    }
  }
}

// =================== combine kernel (round-4 verbatim) ===================
__global__ __launch_bounds__(256) void combine_kernel(
    const float* __restrict__ ea, const int* __restrict__ eidx,
    const unsigned short* __restrict__ wq_ws,
    const float* __restrict__ wsS, const float* __restrict__ wsR,
    float* __restrict__ out)
{
  const int tid = threadIdx.x;
  const int e = blockIdx.x * 256 + tid;
  const int s = eidx[e];
  const int r = eidx[NE + e];
  const float4 y = ld4(ea + (size_t)e*4);

  float accS = 0.f, accR = 0.f;
  const float* Sb = wsS + (size_t)s*768;
  const float* Rb = wsR + (size_t)r*768;
  for (int uq = 0; uq < 16; ++uq) {
    const float* Sr = Sb + uq*48;
    const float* Rr = Rb + uq*48;
    const float4 bsS=ld4(Sr+0),  sv0=ld4(Sr+4),  sv1=ld4(Sr+8),  sv2=ld4(Sr+12);
    const float4 qa0=ld4(Sr+16), qa1=ld4(Sr+20);
    const float4 ra00=ld4(Sr+24),ra01=ld4(Sr+28),ra02=ld4(Sr+32);
    const float4 ra10=ld4(Sr+36),ra11=ld4(Sr+40),ra12=ld4(Sr+44);
    const float4 bsR=ld4(Rr+0),  rv0=ld4(Rr+4),  rv1=ld4(Rr+8),  rv2=ld4(Rr+12);
    const float4 qb0=ld4(Rr+16), qb1=ld4(Rr+20);
    const float4 rb00=ld4(Rr+24),rb01=ld4(Rr+28),rb02=ld4(Rr+32);
    const float4 rb10=ld4(Rr+36),rb11=ld4(Rr+40),rb12=ld4(Rr+44);

    float wq[16];
    #pragma unroll
    for (int m = 0; m < 4; ++m)
      #pragma unroll
      for (int d = 0; d < 4; ++d)
        wq[m*4+d] = b2f(wq_ws[(size_t)(m*64 + uq*4 + d)*NE + e]);

    #pragma unroll
    for (int d = 0; d < 4; ++d) {
      const float bs = C4(bsS,d) + C4(bsR,d);
      const float b0 = C4(sv0,d) + C4(rv0,d);
      const float b1 = C4(sv1,d) + C4(rv1,d);
      const float b2 = C4(sv2,d) + C4(rv2,d);
      const float bvy = b0*y.y + b1*y.z + b2*y.w;
      const float m0 = wq[d]    * bs * y.x;
      const float m1 = wq[4+d]  * bvy;
      const float m2 = wq[8+d]  * bs;
      const float m3 = wq[12+d] * y.x;
      accS += m0*C4(qa0,d) + m1*C4(qa1,d)
            + m2*(y.y*C4(ra00,d) + y.z*C4(ra01,d) + y.w*C4(ra02,d))
            + m3*(b0*C4(ra10,d) + b1*C4(ra11,d) + b2*C4(ra12,d));
      accR += m0*C4(qb0,d) + m1*C4(qb1,d)
            + m2*(y.y*C4(rb00,d) + y.z*C4(rb01,d) + y.w*C4(rb02,d))
            + m3*(b0*C4(rb10,d) + b1*C4(rb11,d) + b2*C4(rb12,d));
    }
  }
  const float pj = FINALS * (accS + accR);
  out[NN*4 + e] = pj;
  atomicAdd(out + (size_t)r*4, pj);
  atomicAdd(out + (size_t)s*4, -pj);
}

extern "C" void kernel_launch(void* const* d_in, const int* in_sizes, int n_in,
                              void* d_out, int out_size, void* d_ws, size_t ws_size,
                              hipStream_t stream) {
  (void)in_sizes; (void)n_in; (void)out_size; (void)ws_size;
  const float* node_feats  = (const float*)d_in[1];
  const float* edge_attrs  = (const float*)d_in[2];
  const float* edge_feats  = (const float*)d_in[3];
  const float* field_feats = (const float*)d_in[4];
  const int*   edge_index  = (const int*)  d_in[5];
  const float* W1s  = (const float*)d_in[6];
  const float* W1v  = (const float*)d_in[7];
  const float* W2s  = (const float*)d_in[8];
  const float* W2v  = (const float*)d_in[9];
  const float* mw1  = (const float*)d_in[10];
  const float* mw2  = (const float*)d_in[11];
  const float* mw3  = (const float*)d_in[12];
  const float* mw4  = (const float*)d_in[13];
  const float* Wvss = (const float*)d_in[14];
  const float* Wvsv = (const float*)d_in[15];
  const float* Wvrs = (const float*)d_in[16];
  const float* Wvrv = (const float*)d_in[17];
  const float* Wfs0 = (const float*)d_in[18];
  const float* Wfs1 = (const float*)d_in[19];
  const float* Wfr0 = (const float*)d_in[20];
  const float* Wfr1 = (const float*)d_in[21];
  // d_in[22]/d_in[23] feed only mp0 which charges overwrite -> dead.
  const float* Wmsv = (const float*)d_in[24];
  const float* Wmvs = (const float*)d_in[25];

  float* out = (float*)d_out;
  float* wsS = (float*)d_ws;                              // 10000*768 f32
  float* wsR = wsS + (size_t)NN*768;                      // 10000*768 f32 (61.44 MB)
  unsigned short* wq_ws = (unsigned short*)(wsR + (size_t)NN*768);  // 256*NE bf16 (82 MB)

  hipLaunchKernelGGL(node_kernel, dim3(314), dim3(256), 0, stream,
      node_feats, field_feats, W1s, W1v, W2s, W2v, Wvss, Wvsv, Wvrs, Wvrv,
      Wfs0, Wfs1, Wfr0, Wfr1, Wmsv, Wmvs, wsS, wsR, out);
  hipLaunchKernelGGL(mlp_kernel, dim3(NE/128), dim3(256), 0, stream,
      edge_feats, mw1, mw2, mw3, mw4, wq_ws);
  hipLaunchKernelGGL(combine_kernel, dim3(NE/256), dim3(256), 0, stream,
      edge_attrs, edge_index, wq_ws, wsS, wsR, out);
}